// Round 6
// baseline (216.540 us; speedup 1.0000x reference)
//
#include <hip/hip_runtime.h>

#define S 2048
#define F 1024
#define H 16
#define DH 64
#define NH (H * DH)   // 1024

typedef __attribute__((ext_vector_type(8))) short bf16x8;
typedef __attribute__((ext_vector_type(4))) float f32x4;

// score pre-scale folded into q at projection: 1/sqrt(64) * log2(e)
#define QSCALE 0.1803368801111244f

__device__ __forceinline__ ushort f2bf(float f) {
  unsigned u = __float_as_uint(f);
  u = (u + 0x7FFFu + ((u >> 16) & 1u)) >> 16;
  return (ushort)u;
}
__device__ __forceinline__ float bf2f(ushort u) {
  return __uint_as_float(((unsigned)u) << 16);
}
// 2^x via v_exp_f32 (s_nop guards the TRANS-use hazard across the asm edge)
__device__ __forceinline__ float ex2(float x) {
  float r;
  asm volatile("v_exp_f32 %0, %1\ns_nop 0" : "=v"(r) : "v"(x));
  return r;
}

__device__ __forceinline__ void gload16(const void* g, void* l) {
  __builtin_amdgcn_global_load_lds(
      (const __attribute__((address_space(1))) void*)g,
      (__attribute__((address_space(3))) void*)l, 16, 0, 0);
}

// swizzled bf16x8 fragment read from a [rows][128B] LDS tile.
__device__ __forceinline__ bf16x8 ldsT(const ushort* buf, int row, int kbyte) {
  return *(const bf16x8*)((const char*)buf + row * 128 +
                          (kbyte ^ ((row & 7) << 4)));
}

// ---------------------------------------------------------------------------
// prep: fp32->bf16 convert of inq & pos + 5 weight transpose-converts.
// blocks [0,2048): conv inq; [2048,4096): conv pos; [4096,5376): tconv x5
// ---------------------------------------------------------------------------
__global__ __launch_bounds__(256) void prep(
    const float* __restrict__ inq, const float* __restrict__ pos,
    const float* __restrict__ Wq, const float* __restrict__ Wk,
    const float* __restrict__ Wv, const float* __restrict__ Wr,
    const float* __restrict__ Wo, ushort* __restrict__ A_bf,
    ushort* __restrict__ P_bf, ushort* __restrict__ Wqkv,
    ushort* __restrict__ Wrt, ushort* __restrict__ Wot) {
  __shared__ ushort T[64][72];
  const int b = blockIdx.x;
  const int t = threadIdx.x;
  if (b < 4096) {
    const float* src = (b < 2048) ? inq : pos;
    ushort* dst = (b < 2048) ? A_bf : P_bf;
    const int i = ((b & 2047) * 256 + t) * 4;
    const float4 v = *(const float4*)(src + i);
    ushort4 u;
    u.x = f2bf(v.x); u.y = f2bf(v.y); u.z = f2bf(v.z); u.w = f2bf(v.w);
    *(ushort4*)(dst + i) = u;
    return;
  }
  const int bb = b - 4096;
  const int which = bb >> 8;
  const int sub = bb & 255;
  const float* src = which == 0 ? Wq
                     : which == 1 ? Wk
                     : which == 2 ? Wv
                     : which == 3 ? Wr : Wo;
  ushort* dst = which == 0 ? Wqkv
                : which == 1 ? Wqkv + 1024 * 1024
                : which == 2 ? Wqkv + 2048 * 1024
                : which == 3 ? Wrt : Wot;
  const int r0 = (sub >> 4) * 64, c0 = (sub & 15) * 64;
#pragma unroll
  for (int q = 0; q < 4; ++q) {
    const int row = q * 16 + (t >> 4);
    const int col = (t & 15) * 4;
    const float4 v = *(const float4*)(src + (size_t)(r0 + row) * 1024 + c0 + col);
    T[row][col + 0] = f2bf(v.x);
    T[row][col + 1] = f2bf(v.y);
    T[row][col + 2] = f2bf(v.z);
    T[row][col + 3] = f2bf(v.w);
  }
  __syncthreads();
#pragma unroll
  for (int q = 0; q < 4; ++q) {
    const int orow = q * 16 + (t >> 4);
    const int ocol = (t & 15) * 4;
    ushort4 u;
    u.x = T[ocol + 0][orow];
    u.y = T[ocol + 1][orow];
    u.z = T[ocol + 2][orow];
    u.w = T[ocol + 3][orow];
    *(ushort4*)(dst + (size_t)(c0 + orow) * 1024 + r0 + ocol) = u;
  }
}

// ---------------------------------------------------------------------------
// bf16 MFMA GEMM, tile 128x128, BK=64, 4 waves (2x2, each 64x64), dbuf
// global_load_lds (m97 structure). K = 1024, M = 2048 fixed.
// EPI 0 (QKVR, grid.z: z0 = A0 x B0 N=3072 QKV bands; z1 = A1 x B1 N=1024 R):
//   Q band -> o0 = (v+rwb)*QSCALE, o1 = (v+rrb)*QSCALE (bf16)
//   K band -> o2 (bf16);  V band -> o3 transposed [NH][S] (bf16);  R -> o4
// EPI 1: fp32 out + bias -> of   (O projection)
// ---------------------------------------------------------------------------
template <int EPI>
__global__ __launch_bounds__(256, 2) void mm128(
    const ushort* __restrict__ A0, const ushort* __restrict__ A1,
    const ushort* __restrict__ B0, const ushort* __restrict__ B1,
    const float* __restrict__ c0, const float* __restrict__ c1,
    const float* __restrict__ c2, const float* __restrict__ c3,
    const float* __restrict__ c4, const float* __restrict__ c5,
    ushort* __restrict__ o0, ushort* __restrict__ o1, ushort* __restrict__ o2,
    ushort* __restrict__ o3, ushort* __restrict__ o4, float* __restrict__ of) {
  __shared__ __align__(16) ushort Asb[2][128 * 64];
  __shared__ __align__(16) ushort Bsb[2][128 * 64];
  const int tid = threadIdx.x;
  const int l = tid & 63, w = tid >> 6;
  const int wm = w >> 1, wn = w & 1;
  const int bz = (EPI == 0) ? blockIdx.z : 0;
  if (EPI == 0 && bz == 1 && blockIdx.x >= 8) return;
  const ushort* Ause = (EPI == 0 && bz) ? A1 : A0;
  const ushort* Buse = (EPI == 0 && bz) ? B1 : B0;
  const int m0 = blockIdx.y * 128, n0 = blockIdx.x * 128;
  const int K = 1024;

  f32x4 acc[4][4];
#pragma unroll
  for (int m = 0; m < 4; ++m)
#pragma unroll
    for (int n = 0; n < 4; ++n) acc[m][n] = (f32x4){0.f, 0.f, 0.f, 0.f};

#define M128_STAGE(c, kt)                                                      \
  {                                                                            \
    const int k0 = (kt) * 64;                                                  \
    _Pragma("unroll") for (int i = 0; i < 4; ++i) {                            \
      const int LB = (i * 256 + tid) * 16, row = LB >> 7, rb_ = LB & 127;      \
      const int tb = rb_ ^ ((row & 7) << 4);                                   \
      gload16((const char*)Ause + ((size_t)(m0 + row) * K + k0) * 2 + tb,      \
              (char*)Asb[c] + LB);                                             \
      gload16((const char*)Buse + ((size_t)(n0 + row) * K + k0) * 2 + tb,      \
              (char*)Bsb[c] + LB);                                             \
    }                                                                          \
  }

  M128_STAGE(0, 0);
  __syncthreads();
  int cur = 0;
#pragma unroll 1
  for (int kt = 0; kt < 16; ++kt) {
    if (kt + 1 < 16) M128_STAGE(cur ^ 1, kt + 1);
#pragma unroll
    for (int ks = 0; ks < 2; ++ks) {
      bf16x8 af[4], bfr[4];
#pragma unroll
      for (int m = 0; m < 4; ++m)
        af[m] = ldsT(Asb[cur], wm * 64 + m * 16 + (l & 15),
                     ks * 64 + (l >> 4) * 16);
#pragma unroll
      for (int n = 0; n < 4; ++n)
        bfr[n] = ldsT(Bsb[cur], wn * 64 + n * 16 + (l & 15),
                      ks * 64 + (l >> 4) * 16);
      __builtin_amdgcn_s_setprio(1);
#pragma unroll
      for (int m = 0; m < 4; ++m)
#pragma unroll
        for (int n = 0; n < 4; ++n)
          acc[m][n] = __builtin_amdgcn_mfma_f32_16x16x32_bf16(
              af[m], bfr[n], acc[m][n], 0, 0, 0);
      __builtin_amdgcn_s_setprio(0);
    }
    __syncthreads();
    cur ^= 1;
  }

#pragma unroll
  for (int m = 0; m < 4; ++m)
#pragma unroll
    for (int n = 0; n < 4; ++n) {
      const int rowb = m0 + wm * 64 + m * 16 + (l >> 4) * 4;
      const int colg = n0 + wn * 64 + n * 16 + (l & 15);
      if constexpr (EPI == 1) {
        const float bs = c0[colg];
#pragma unroll
        for (int r = 0; r < 4; ++r)
          of[(size_t)(rowb + r) * 1024 + colg] = acc[m][n][r] + bs;
      } else if (bz == 1) {
        const float bs = c5[colg];
#pragma unroll
        for (int r = 0; r < 4; ++r)
          o4[(size_t)(rowb + r) * NH + colg] = f2bf(acc[m][n][r] + bs);
      } else {
        const int band = colg >> 10;
        const int colm = colg & 1023;
        if (band == 0) {
          const float bs = c0[colm], vw = c1[colm], vr = c2[colm];
#pragma unroll
          for (int r = 0; r < 4; ++r) {
            const float v = acc[m][n][r] + bs;
            o0[(size_t)(rowb + r) * NH + colm] = f2bf((v + vw) * QSCALE);
            o1[(size_t)(rowb + r) * NH + colm] = f2bf((v + vr) * QSCALE);
          }
        } else if (band == 1) {
          const float bs = c3[colm];
#pragma unroll
          for (int r = 0; r < 4; ++r)
            o2[(size_t)(rowb + r) * NH + colm] = f2bf(acc[m][n][r] + bs);
        } else {
          const float bs = c4[colm];
          ushort4 u;
          u.x = f2bf(acc[m][n][0] + bs);
          u.y = f2bf(acc[m][n][1] + bs);
          u.z = f2bf(acc[m][n][2] + bs);
          u.w = f2bf(acc[m][n][3] + bs);
          *(ushort4*)(o3 + (size_t)colm * S + rowb) = u;
        }
      }
    }
}

// ---------------------------------------------------------------------------
// Fused rel-attention, split-j halves, log2-space online softmax with
// defer-max (THR=8). q operands pre-scaled by QSCALE at projection.
// ---------------------------------------------------------------------------
__global__ __launch_bounds__(256, 2) void attn_mfma(
    const ushort* __restrict__ qw, const ushort* __restrict__ qr,
    const ushort* __restrict__ kb, const ushort* __restrict__ vt,
    const ushort* __restrict__ rb, float* __restrict__ accA,
    float* __restrict__ accB, float* __restrict__ mA, float* __restrict__ lA,
    float* __restrict__ mB, float* __restrict__ lB) {
  __shared__ __align__(16) ushort Kb[2][64 * 64];
  __shared__ __align__(16) ushort Vb[2][64 * 64];
  __shared__ __align__(16) ushort Rb[2][64 * 64];
  __shared__ __align__(16) ushort BDb[2][64 * 68];  // pad 68: conflict-free shear
  __shared__ __align__(16) ushort Pb[4][16 * 64];

  const int bx = blockIdx.x;
  const int it = 31 - (bx >> 5);
  const int half = (bx >> 4) & 1;
  const int h = bx & 15;
  const int i0 = it * 64;
  const int tid = threadIdx.x;
  const int l = tid & 63, w = tid >> 6;
  const int lo = (it + 1) >> 1;
  const int fr_base = w * 16 + (l >> 4) * 4;

  float* __restrict__ accX = half ? accB : accA;
  float* __restrict__ mX = half ? mB : mA;
  float* __restrict__ lX = half ? lB : lA;

  if (half == 1 && lo == 0) {
#pragma unroll
    for (int n = 0; n < 4; ++n)
#pragma unroll
      for (int r = 0; r < 4; ++r)
        accX[(size_t)(i0 + fr_base + r) * NH + h * 64 + n * 16 + (l & 15)] =
            0.f;
    if ((l & 15) == 0)
#pragma unroll
      for (int r = 0; r < 4; ++r) {
        mX[(i0 + fr_base + r) * H + h] = -1e30f;
        lX[(i0 + fr_base + r) * H + h] = 0.f;
      }
    return;
  }

  const int jstart = half ? (lo - 1) : it;
  const int jend = half ? 0 : lo;
  const int tp0 = it - jstart;

#pragma unroll
  for (int i = 0; i < 2; ++i) {
    const int LB = (i * 256 + tid) * 16, row = LB >> 7, rb_ = LB & 127;
    gload16((const char*)qw + ((size_t)(i0 + row) * NH + h * 64) * 2 + rb_,
            (char*)Kb[0] + LB);
    gload16((const char*)qr + ((size_t)(i0 + row) * NH + h * 64) * 2 + rb_,
            (char*)Kb[1] + LB);
  }
  __syncthreads();
  bf16x8 qwf[2], qrf[2];
#pragma unroll
  for (int ks = 0; ks < 2; ++ks) {
    const int row = w * 16 + (l & 15);
    const int kbyte = ks * 64 + (l >> 4) * 16;
    qwf[ks] = *(const bf16x8*)((const char*)Kb[0] + row * 128 + kbyte);
    qrf[ks] = *(const bf16x8*)((const char*)Kb[1] + row * 128 + kbyte);
  }
  __syncthreads();

  f32x4 acc_o[4];
#pragma unroll
  for (int n = 0; n < 4; ++n) acc_o[n] = (f32x4){0.f, 0.f, 0.f, 0.f};
  f32x4 acc_l = (f32x4){0.f, 0.f, 0.f, 0.f};
  float m_r[4] = {-1e30f, -1e30f, -1e30f, -1e30f};

  const short one_bf = (short)0x3F80;
  const bf16x8 ones = {one_bf, one_bf, one_bf, one_bf,
                       one_bf, one_bf, one_bf, one_bf};

#define AT_STAGE(c, jt_)                                                       \
  {                                                                            \
    const int j0 = (jt_) * 64;                                                 \
    const int tp_ = it - (jt_);                                                \
    _Pragma("unroll") for (int i = 0; i < 2; ++i) {                            \
      const int LB = (i * 256 + tid) * 16, row = LB >> 7, rb_ = LB & 127;      \
      const int tb = rb_ ^ ((row & 7) << 4);                                   \
      gload16((const char*)kb + ((size_t)(j0 + row) * NH + h * 64) * 2 + tb,   \
              (char*)Kb[c] + LB);                                              \
      gload16((const char*)vt + ((size_t)(h * 64 + row) * S + j0) * 2 + tb,    \
              (char*)Vb[c] + LB);                                              \
      gload16((const char*)rb +                                                \
                  ((size_t)(S - 1 - 64 * tp_ - row) * NH + h * 64) * 2 + tb,   \
              (char*)Rb[c] + LB);                                              \
    }                                                                          \
  }

  if (half) {
#pragma unroll
    for (int i = 0; i < 2; ++i) {
      const int LB = (i * 256 + tid) * 16, row = LB >> 7, rb_ = LB & 127;
      const int tb = rb_ ^ ((row & 7) << 4);
      gload16((const char*)rb +
                  ((size_t)(S - 1 - 64 * (tp0 - 1) - row) * NH + h * 64) * 2 +
                  tb,
              (char*)Rb[1] + LB);
    }
  }
  AT_STAGE(0, jstart);
  __syncthreads();
  if (half) {
    f32x4 bd[4];
#pragma unroll
    for (int n = 0; n < 4; ++n) bd[n] = (f32x4){0.f, 0.f, 0.f, 0.f};
#pragma unroll
    for (int ks = 0; ks < 2; ++ks) {
      bf16x8 rf[4];
#pragma unroll
      for (int n = 0; n < 4; ++n)
        rf[n] = ldsT(Rb[1], n * 16 + (l & 15), ks * 64 + (l >> 4) * 16);
      __builtin_amdgcn_s_setprio(1);
#pragma unroll
      for (int n = 0; n < 4; ++n)
        bd[n] = __builtin_amdgcn_mfma_f32_16x16x32_bf16(qrf[ks], rf[n], bd[n],
                                                        0, 0, 0);
      __builtin_amdgcn_s_setprio(0);
    }
    ushort* B = BDb[(tp0 - 1) & 1];
#pragma unroll
    for (int n = 0; n < 4; ++n)
#pragma unroll
      for (int r = 0; r < 4; ++r)
        B[(fr_base + r) * 68 + n * 16 + (l & 15)] = f2bf(bd[n][r]);
    __syncthreads();
  }

  int cur = 0;
  for (int jt = jstart; jt >= jend; --jt) {
    const int tp = it - jt;
    if (jt > jend) AT_STAGE(cur ^ 1, jt - 1);

    // --- BDlag tile tp
    f32x4 bd[4];
#pragma unroll
    for (int n = 0; n < 4; ++n) bd[n] = (f32x4){0.f, 0.f, 0.f, 0.f};
#pragma unroll
    for (int ks = 0; ks < 2; ++ks) {
      bf16x8 rf[4];
#pragma unroll
      for (int n = 0; n < 4; ++n)
        rf[n] = ldsT(Rb[cur], n * 16 + (l & 15), ks * 64 + (l >> 4) * 16);
      __builtin_amdgcn_s_setprio(1);
#pragma unroll
      for (int n = 0; n < 4; ++n)
        bd[n] = __builtin_amdgcn_mfma_f32_16x16x32_bf16(qrf[ks], rf[n], bd[n],
                                                        0, 0, 0);
      __builtin_amdgcn_s_setprio(0);
    }
    {
      ushort* B = BDb[tp & 1];
#pragma unroll
      for (int n = 0; n < 4; ++n)
#pragma unroll
        for (int r = 0; r < 4; ++r)
          B[(fr_base + r) * 68 + n * 16 + (l & 15)] = f2bf(bd[n][r]);
    }

    // --- AC tile
    f32x4 sa[4];
#pragma unroll
    for (int n = 0; n < 4; ++n) sa[n] = (f32x4){0.f, 0.f, 0.f, 0.f};
#pragma unroll
    for (int ks = 0; ks < 2; ++ks) {
      bf16x8 kf[4];
#pragma unroll
      for (int n = 0; n < 4; ++n)
        kf[n] = ldsT(Kb[cur], n * 16 + (l & 15), ks * 64 + (l >> 4) * 16);
      __builtin_amdgcn_s_setprio(1);
#pragma unroll
      for (int n = 0; n < 4; ++n)
        sa[n] = __builtin_amdgcn_mfma_f32_16x16x32_bf16(qwf[ks], kf[n], sa[n],
                                                        0, 0, 0);
      __builtin_amdgcn_s_setprio(0);
    }

    // --- shear BD + mask + online softmax (log2 space, defer-max)
    const ushort* Bnew = BDb[tp & 1];
    const ushort* Bold = BDb[(tp & 1) ^ 1];
    float p[4][4];
    float rmax[4] = {-1e30f, -1e30f, -1e30f, -1e30f};
#pragma unroll
    for (int n = 0; n < 4; ++n)
#pragma unroll
      for (int r = 0; r < 4; ++r) {
        const int fr = fr_base + r;
        const int jj = n * 16 + (l & 15);
        const int u = 64 + fr - jj;
        const float bdv =
            bf2f((u >= 64) ? Bnew[fr * 68 + (u - 64)] : Bold[fr * 68 + u]);
        float s = sa[n][r] + bdv;  // already in log2 units (q pre-scaled)
        if (tp == 0 && jj > fr) s = -1e30f;
        p[n][r] = s;
        rmax[r] = fmaxf(rmax[r], s);
      }
#pragma unroll
    for (int off = 1; off < 16; off <<= 1)
#pragma unroll
      for (int r = 0; r < 4; ++r)
        rmax[r] = fmaxf(rmax[r], __shfl_xor(rmax[r], off, 64));
    int grow = 0;
#pragma unroll
    for (int r = 0; r < 4; ++r) grow |= (rmax[r] > m_r[r] + 8.f);
    if (__any(grow)) {
      float corr[4];
#pragma unroll
      for (int r = 0; r < 4; ++r) {
        const float mn = fmaxf(m_r[r], rmax[r]);
        corr[r] = ex2(m_r[r] - mn);
        m_r[r] = mn;
      }
#pragma unroll
      for (int r = 0; r < 4; ++r) acc_l[r] *= corr[r];
#pragma unroll
      for (int n = 0; n < 4; ++n)
#pragma unroll
        for (int r = 0; r < 4; ++r) acc_o[n][r] *= corr[r];
    }
#pragma unroll
    for (int n = 0; n < 4; ++n)
#pragma unroll
      for (int r = 0; r < 4; ++r) p[n][r] = ex2(p[n][r] - m_r[r]);

    // --- write P (swizzled, wave-private)
    {
      ushort* P = Pb[w];
#pragma unroll
      for (int n = 0; n < 4; ++n)
#pragma unroll
        for (int r = 0; r < 4; ++r) {
          const int row = (l >> 4) * 4 + r;
          const int colb = (n * 16 + (l & 15)) * 2;
          *(ushort*)((char*)P + row * 128 + (colb ^ ((row & 7) << 4))) =
              f2bf(p[n][r]);
        }
    }

    // --- PV + l accumulation
#pragma unroll
    for (int ks = 0; ks < 2; ++ks) {
      const int prow = l & 15;
      const bf16x8 pf = *(const bf16x8*)(
          (const char*)Pb[w] + prow * 128 +
          ((ks * 64 + (l >> 4) * 16) ^ ((prow & 7) << 4)));
      bf16x8 vf[4];
#pragma unroll
      for (int n = 0; n < 4; ++n)
        vf[n] = ldsT(Vb[cur], n * 16 + (l & 15), ks * 64 + (l >> 4) * 16);
      __builtin_amdgcn_s_setprio(1);
#pragma unroll
      for (int n = 0; n < 4; ++n)
        acc_o[n] = __builtin_amdgcn_mfma_f32_16x16x32_bf16(pf, vf[n], acc_o[n],
                                                           0, 0, 0);
      acc_l = __builtin_amdgcn_mfma_f32_16x16x32_bf16(pf, ones, acc_l, 0, 0, 0);
      __builtin_amdgcn_s_setprio(0);
    }
    __syncthreads();
    cur ^= 1;
  }

#pragma unroll
  for (int n = 0; n < 4; ++n)
#pragma unroll
    for (int r = 0; r < 4; ++r)
      accX[(size_t)(i0 + fr_base + r) * NH + h * 64 + n * 16 + (l & 15)] =
          acc_o[n][r];
  if ((l & 15) == 0)
#pragma unroll
    for (int r = 0; r < 4; ++r) {
      mX[(i0 + fr_base + r) * H + h] = m_r[r];
      lX[(i0 + fr_base + r) * H + h] = acc_l[r];
    }
}

// ---------------------------------------------------------------------------
// combine halves (m values are in log2 space)
// ---------------------------------------------------------------------------
__global__ __launch_bounds__(256) void combine_halves(
    const float* __restrict__ accA, const float* __restrict__ accB,
    const float* __restrict__ mA, const float* __restrict__ lA,
    const float* __restrict__ mB, const float* __restrict__ lB,
    ushort* __restrict__ ab) {
  const int idx = blockIdx.x * 256 + threadIdx.x;
  const int base = idx * 4;
  const int i = base >> 10;
  const int h = (base & 1023) >> 6;
  const float4 a = *(const float4*)(accA + base);
  const float4 b = *(const float4*)(accB + base);
  const float ma = mA[i * H + h], la = lA[i * H + h];
  const float mb = mB[i * H + h], lb = lB[i * H + h];
  const float M = fmaxf(ma, mb);
  const float ea = ex2(ma - M), eb = ex2(mb - M);
  const float inv = 1.f / (la * ea + lb * eb);
  ushort4 u;
  u.x = f2bf((a.x * ea + b.x * eb) * inv);
  u.y = f2bf((a.y * ea + b.y * eb) * inv);
  u.z = f2bf((a.z * ea + b.z * eb) * inv);
  u.w = f2bf((a.w * ea + b.w * eb) * inv);
  *(ushort4*)(ab + base) = u;
}

// ---------------------------------------------------------------------------
extern "C" void kernel_launch(void* const* d_in, const int* in_sizes, int n_in,
                              void* d_out, int out_size, void* d_ws,
                              size_t ws_size, hipStream_t stream) {
  const float* inq = (const float*)d_in[0];
  const float* pos = (const float*)d_in[1];
  const float* rwb = (const float*)d_in[2];
  const float* rrb = (const float*)d_in[3];
  const float* Wq = (const float*)d_in[4];
  const float* bq = (const float*)d_in[5];
  const float* Wk = (const float*)d_in[6];
  const float* bk = (const float*)d_in[7];
  const float* Wv = (const float*)d_in[8];
  const float* bv = (const float*)d_in[9];
  const float* Wr = (const float*)d_in[10];
  const float* br = (const float*)d_in[11];
  const float* Wo = (const float*)d_in[12];
  const float* bo = (const float*)d_in[13];

  char* ws = (char*)d_ws;
  const size_t MB = 1024 * 1024;
  ushort* A_bf = (ushort*)(ws + 0 * MB);   // [S][F] bf16; later reused as ab
  ushort* P_bf = (ushort*)(ws + 4 * MB);   // [S][F] bf16 (dead after QKVR GEMM)
  ushort* Wqkv = (ushort*)(ws + 8 * MB);   // [3072][1024] (dead after GEMM)
  ushort* Wrt = (ushort*)(ws + 14 * MB);   // [NH][F]
  ushort* Wot = (ushort*)(ws + 16 * MB);   // [F][NH]
  ushort* qwp = (ushort*)(ws + 18 * MB);   // [S][NH]
  ushort* qrp = (ushort*)(ws + 22 * MB);
  ushort* kbp = (ushort*)(ws + 26 * MB);
  ushort* vtp = (ushort*)(ws + 30 * MB);   // [NH][S]
  ushort* rbp = (ushort*)(ws + 34 * MB);
  float* mlA = (float*)(ws + 4 * MB);      // aliases P_bf (dead by attn)
  float* mA = mlA + 0 * 32768;
  float* lA = mlA + 1 * 32768;
  float* mB = mlA + 2 * 32768;
  float* lB = mlA + 3 * 32768;
  float* accA = (float*)(ws + 6 * MB);     // aliases Wqkv region (dead by attn)
  float* accB = (float*)(ws + 38 * MB);
  ushort* abp = A_bf;

  prep<<<5376, 256, 0, stream>>>(inq, pos, Wq, Wk, Wv, Wr, Wo, A_bf, P_bf,
                                 Wqkv, Wrt, Wot);

  mm128<0><<<dim3(24, 16, 2), 256, 0, stream>>>(
      A_bf, P_bf, Wqkv, Wrt, bq, rwb, rrb, bk, bv, br, qwp, qrp, kbp, vtp, rbp,
      nullptr);

  attn_mfma<<<1024, 256, 0, stream>>>(qwp, qrp, kbp, vtp, rbp, accA, accB, mA,
                                      lA, mB, lB);
  combine_halves<<<2048, 256, 0, stream>>>(accA, accB, mA, lA, mB, lB, abp);

  mm128<1><<<dim3(8, 16, 1), 256, 0, stream>>>(
      abp, nullptr, Wot, nullptr, bo, nullptr, nullptr, nullptr, nullptr,
      nullptr, nullptr, nullptr, nullptr, nullptr, nullptr, (float*)d_out);
}

// Round 7
// 194.401 us; speedup vs baseline: 1.1139x; 1.1139x over previous
//
#include <hip/hip_runtime.h>

#define S 2048
#define F 1024
#define H 16
#define DH 64
#define NH (H * DH)   // 1024

typedef __attribute__((ext_vector_type(8))) short bf16x8;
typedef __attribute__((ext_vector_type(4))) float f32x4;

// score pre-scale folded into q at projection: 1/sqrt(64) * log2(e)
#define QSCALE 0.1803368801111244f

__device__ __forceinline__ ushort f2bf(float f) {
  unsigned u = __float_as_uint(f);
  u = (u + 0x7FFFu + ((u >> 16) & 1u)) >> 16;
  return (ushort)u;
}
__device__ __forceinline__ float bf2f(ushort u) {
  return __uint_as_float(((unsigned)u) << 16);
}

__device__ __forceinline__ void gload16(const void* g, void* l) {
  __builtin_amdgcn_global_load_lds(
      (const __attribute__((address_space(1))) void*)g,
      (__attribute__((address_space(3))) void*)l, 16, 0, 0);
}

// swizzled bf16x8 fragment read from a [rows][128B] LDS tile.
__device__ __forceinline__ bf16x8 ldsT(const ushort* buf, int row, int kbyte) {
  return *(const bf16x8*)((const char*)buf + row * 128 +
                          (kbyte ^ ((row & 7) << 4)));
}

// ---------------------------------------------------------------------------
// prep: fp32->bf16 convert of inq & pos + 5 weight transpose-converts.
// ---------------------------------------------------------------------------
__global__ __launch_bounds__(256) void prep(
    const float* __restrict__ inq, const float* __restrict__ pos,
    const float* __restrict__ Wq, const float* __restrict__ Wk,
    const float* __restrict__ Wv, const float* __restrict__ Wr,
    const float* __restrict__ Wo, ushort* __restrict__ A_bf,
    ushort* __restrict__ P_bf, ushort* __restrict__ Wqkv,
    ushort* __restrict__ Wrt, ushort* __restrict__ Wot) {
  __shared__ ushort T[64][72];
  const int b = blockIdx.x;
  const int t = threadIdx.x;
  if (b < 4096) {
    const float* src = (b < 2048) ? inq : pos;
    ushort* dst = (b < 2048) ? A_bf : P_bf;
    const int i = ((b & 2047) * 256 + t) * 4;
    const float4 v = *(const float4*)(src + i);
    ushort4 u;
    u.x = f2bf(v.x); u.y = f2bf(v.y); u.z = f2bf(v.z); u.w = f2bf(v.w);
    *(ushort4*)(dst + i) = u;
    return;
  }
  const int bb = b - 4096;
  const int which = bb >> 8;
  const int sub = bb & 255;
  const float* src = which == 0 ? Wq
                     : which == 1 ? Wk
                     : which == 2 ? Wv
                     : which == 3 ? Wr : Wo;
  ushort* dst = which == 0 ? Wqkv
                : which == 1 ? Wqkv + 1024 * 1024
                : which == 2 ? Wqkv + 2048 * 1024
                : which == 3 ? Wrt : Wot;
  const int r0 = (sub >> 4) * 64, c0 = (sub & 15) * 64;
#pragma unroll
  for (int q = 0; q < 4; ++q) {
    const int row = q * 16 + (t >> 4);
    const int col = (t & 15) * 4;
    const float4 v = *(const float4*)(src + (size_t)(r0 + row) * 1024 + c0 + col);
    T[row][col + 0] = f2bf(v.x);
    T[row][col + 1] = f2bf(v.y);
    T[row][col + 2] = f2bf(v.z);
    T[row][col + 3] = f2bf(v.w);
  }
  __syncthreads();
#pragma unroll
  for (int q = 0; q < 4; ++q) {
    const int orow = q * 16 + (t >> 4);
    const int ocol = (t & 15) * 4;
    ushort4 u;
    u.x = T[ocol + 0][orow];
    u.y = T[ocol + 1][orow];
    u.z = T[ocol + 2][orow];
    u.w = T[ocol + 3][orow];
    *(ushort4*)(dst + (size_t)(c0 + orow) * 1024 + r0 + ocol) = u;
  }
}

// ---------------------------------------------------------------------------
// bf16 MFMA GEMM, tile 128x128, BK=64, 4 waves, dbuf global_load_lds, with
// bijective XCD swizzle on (x,y). K = 1024, M = 2048.
// EPI 0: QKVR fused (z0: N=3072 QKV bands; z1: N=1024 R, x<8 active)
// EPI 1: fp32 out + bias (O projection, N=1024)
// ---------------------------------------------------------------------------
template <int EPI>
__global__ __launch_bounds__(256, 2) void mm128(
    const ushort* __restrict__ A0, const ushort* __restrict__ A1,
    const ushort* __restrict__ B0, const ushort* __restrict__ B1,
    const float* __restrict__ c0, const float* __restrict__ c1,
    const float* __restrict__ c2, const float* __restrict__ c3,
    const float* __restrict__ c4, const float* __restrict__ c5,
    ushort* __restrict__ o0, ushort* __restrict__ o1, ushort* __restrict__ o2,
    ushort* __restrict__ o3, ushort* __restrict__ o4, float* __restrict__ of) {
  __shared__ __align__(16) ushort Asb[2][128 * 64];
  __shared__ __align__(16) ushort Bsb[2][128 * 64];
  const int tid = threadIdx.x;
  const int l = tid & 63, w = tid >> 6;
  const int wm = w >> 1, wn = w & 1;
  // XCD-aware bijective swizzle (nwg % 8 == 0 in both instantiations)
  constexpr int GX = (EPI == 0) ? 24 : 8;
  constexpr int GY = 16;
  constexpr int CPX = GX * GY / 8;
  const int lin = blockIdx.x + GX * blockIdx.y;
  const int swz = (lin & 7) * CPX + (lin >> 3);
  const int bx2 = swz % GX;
  const int by2 = swz / GX;
  const int bz = (EPI == 0) ? blockIdx.z : 0;
  if (EPI == 0 && bz == 1 && bx2 >= 8) return;
  const ushort* Ause = (EPI == 0 && bz) ? A1 : A0;
  const ushort* Buse = (EPI == 0 && bz) ? B1 : B0;
  const int m0 = by2 * 128, n0 = bx2 * 128;
  const int K = 1024;

  f32x4 acc[4][4];
#pragma unroll
  for (int m = 0; m < 4; ++m)
#pragma unroll
    for (int n = 0; n < 4; ++n) acc[m][n] = (f32x4){0.f, 0.f, 0.f, 0.f};

#define M128_STAGE(c, kt)                                                      \
  {                                                                            \
    const int k0 = (kt) * 64;                                                  \
    _Pragma("unroll") for (int i = 0; i < 4; ++i) {                            \
      const int LB = (i * 256 + tid) * 16, row = LB >> 7, rb_ = LB & 127;      \
      const int tb = rb_ ^ ((row & 7) << 4);                                   \
      gload16((const char*)Ause + ((size_t)(m0 + row) * K + k0) * 2 + tb,      \
              (char*)Asb[c] + LB);                                             \
      gload16((const char*)Buse + ((size_t)(n0 + row) * K + k0) * 2 + tb,      \
              (char*)Bsb[c] + LB);                                             \
    }                                                                          \
  }

  M128_STAGE(0, 0);
  __syncthreads();
  int cur = 0;
#pragma unroll 1
  for (int kt = 0; kt < 16; ++kt) {
    if (kt + 1 < 16) M128_STAGE(cur ^ 1, kt + 1);
#pragma unroll
    for (int ks = 0; ks < 2; ++ks) {
      bf16x8 af[4], bfr[4];
#pragma unroll
      for (int m = 0; m < 4; ++m)
        af[m] = ldsT(Asb[cur], wm * 64 + m * 16 + (l & 15),
                     ks * 64 + (l >> 4) * 16);
#pragma unroll
      for (int n = 0; n < 4; ++n)
        bfr[n] = ldsT(Bsb[cur], wn * 64 + n * 16 + (l & 15),
                      ks * 64 + (l >> 4) * 16);
      __builtin_amdgcn_s_setprio(1);
#pragma unroll
      for (int m = 0; m < 4; ++m)
#pragma unroll
        for (int n = 0; n < 4; ++n)
          acc[m][n] = __builtin_amdgcn_mfma_f32_16x16x32_bf16(
              af[m], bfr[n], acc[m][n], 0, 0, 0);
      __builtin_amdgcn_s_setprio(0);
    }
    __syncthreads();
    cur ^= 1;
  }

#pragma unroll
  for (int m = 0; m < 4; ++m)
#pragma unroll
    for (int n = 0; n < 4; ++n) {
      const int rowb = m0 + wm * 64 + m * 16 + (l >> 4) * 4;
      const int colg = n0 + wn * 64 + n * 16 + (l & 15);
      if constexpr (EPI == 1) {
        const float bs = c0[colg];
#pragma unroll
        for (int r = 0; r < 4; ++r)
          of[(size_t)(rowb + r) * 1024 + colg] = acc[m][n][r] + bs;
      } else if (bz == 1) {
        const float bs = c5[colg];
#pragma unroll
        for (int r = 0; r < 4; ++r)
          o4[(size_t)(rowb + r) * NH + colg] = f2bf(acc[m][n][r] + bs);
      } else {
        const int band = colg >> 10;
        const int colm = colg & 1023;
        if (band == 0) {
          const float bs = c0[colm], vw = c1[colm], vr = c2[colm];
#pragma unroll
          for (int r = 0; r < 4; ++r) {
            const float v = acc[m][n][r] + bs;
            o0[(size_t)(rowb + r) * NH + colm] = f2bf((v + vw) * QSCALE);
            o1[(size_t)(rowb + r) * NH + colm] = f2bf((v + vr) * QSCALE);
          }
        } else if (band == 1) {
          const float bs = c3[colm];
#pragma unroll
          for (int r = 0; r < 4; ++r)
            o2[(size_t)(rowb + r) * NH + colm] = f2bf(acc[m][n][r] + bs);
        } else {
          const float bs = c4[colm];
          ushort4 u;
          u.x = f2bf(acc[m][n][0] + bs);
          u.y = f2bf(acc[m][n][1] + bs);
          u.z = f2bf(acc[m][n][2] + bs);
          u.w = f2bf(acc[m][n][3] + bs);
          *(ushort4*)(o3 + (size_t)colm * S + rowb) = u;
        }
      }
    }
}

// ---------------------------------------------------------------------------
// Fused rel-attention, split-j halves, log2-space softmax with defer-max.
// LDS diet (49 KB -> 3 blocks/CU): K,V single-buffered (staged at step top,
// mid-step barrier drains); R double-buffered; P aliases the dead BD slot.
// ---------------------------------------------------------------------------
__global__ __launch_bounds__(256, 3) void attn_mfma(
    const ushort* __restrict__ qw, const ushort* __restrict__ qr,
    const ushort* __restrict__ kb, const ushort* __restrict__ vt,
    const ushort* __restrict__ rb, float* __restrict__ accA,
    float* __restrict__ accB, float* __restrict__ mA, float* __restrict__ lA,
    float* __restrict__ mB, float* __restrict__ lB) {
  __shared__ __align__(16) ushort Kb[64 * 64];       // 8 KB (also qw landing)
  __shared__ __align__(16) ushort Vb[64 * 64];       // 8 KB (also qr landing)
  __shared__ __align__(16) ushort Rb[2][64 * 64];    // 16 KB
  __shared__ __align__(16) ushort BDb[2][64 * 68];   // 17 KB (+P alias in dead slot)

  const int bx = blockIdx.x;
  const int it = 31 - (bx >> 5);  // big i-tiles dispatched first (LPT)
  const int half = (bx >> 4) & 1;
  const int h = bx & 15;
  const int i0 = it * 64;
  const int tid = threadIdx.x;
  const int l = tid & 63, w = tid >> 6;
  const int lo = (it + 1) >> 1;
  const int fr_base = w * 16 + (l >> 4) * 4;

  float* __restrict__ accX = half ? accB : accA;
  float* __restrict__ mX = half ? mB : mA;
  float* __restrict__ lX = half ? lB : lA;

  if (half == 1 && lo == 0) {  // it==0 halfB: empty -> neutral partials
#pragma unroll
    for (int n = 0; n < 4; ++n)
#pragma unroll
      for (int r = 0; r < 4; ++r)
        accX[(size_t)(i0 + fr_base + r) * NH + h * 64 + n * 16 + (l & 15)] =
            0.f;
    if ((l & 15) == 0)
#pragma unroll
      for (int r = 0; r < 4; ++r) {
        mX[(i0 + fr_base + r) * H + h] = -1e30f;
        lX[(i0 + fr_base + r) * H + h] = 0.f;
      }
    return;
  }

  const int jstart = half ? (lo - 1) : it;
  const int jend = half ? 0 : lo;
  const int tp0 = it - jstart;

  // ---- prologue: qw->Kb, qr->Vb (linear); R(jstart)->Rb[0]; halfB extra
  //      lag tile (tp0-1)->Rb[1]. All gloads overlap; one barrier.
#pragma unroll
  for (int i = 0; i < 2; ++i) {
    const int LB = (i * 256 + tid) * 16, row = LB >> 7, rb_ = LB & 127;
    const int tb = rb_ ^ ((row & 7) << 4);
    gload16((const char*)qw + ((size_t)(i0 + row) * NH + h * 64) * 2 + rb_,
            (char*)Kb + LB);
    gload16((const char*)qr + ((size_t)(i0 + row) * NH + h * 64) * 2 + rb_,
            (char*)Vb + LB);
    gload16((const char*)rb +
                ((size_t)(S - 1 - 64 * tp0 - row) * NH + h * 64) * 2 + tb,
            (char*)Rb[0] + LB);
    if (half)
      gload16((const char*)rb +
                  ((size_t)(S - 1 - 64 * (tp0 - 1) - row) * NH + h * 64) * 2 +
                  tb,
              (char*)Rb[1] + LB);
  }
  __syncthreads();
  bf16x8 qwf[2], qrf[2];
#pragma unroll
  for (int ks = 0; ks < 2; ++ks) {
    const int row = w * 16 + (l & 15);
    const int kbyte = ks * 64 + (l >> 4) * 16;
    qwf[ks] = *(const bf16x8*)((const char*)Kb + row * 128 + kbyte);
    qrf[ks] = *(const bf16x8*)((const char*)Vb + row * 128 + kbyte);
  }
  if (half) {  // BD(tp0-1) from Rb[1] -> BDb slot (tp0-1)&1 (wave-private rows)
    f32x4 bd[4];
#pragma unroll
    for (int n = 0; n < 4; ++n) bd[n] = (f32x4){0.f, 0.f, 0.f, 0.f};
#pragma unroll
    for (int ks = 0; ks < 2; ++ks) {
      bf16x8 rf[4];
#pragma unroll
      for (int n = 0; n < 4; ++n)
        rf[n] = ldsT(Rb[1], n * 16 + (l & 15), ks * 64 + (l >> 4) * 16);
      __builtin_amdgcn_s_setprio(1);
#pragma unroll
      for (int n = 0; n < 4; ++n)
        bd[n] = __builtin_amdgcn_mfma_f32_16x16x32_bf16(qrf[ks], rf[n], bd[n],
                                                        0, 0, 0);
      __builtin_amdgcn_s_setprio(0);
    }
    char* B = (char*)BDb + ((tp0 - 1) & 1) * 8704;
#pragma unroll
    for (int n = 0; n < 4; ++n)
#pragma unroll
      for (int r = 0; r < 4; ++r)
        *(ushort*)(B + (fr_base + r) * 136 + (n * 16 + (l & 15)) * 2) =
            f2bf(bd[n][r]);
  }
  __syncthreads();  // Rb[1]/Kb/Vb reads done before loop restages them

  f32x4 acc_o[4];
#pragma unroll
  for (int n = 0; n < 4; ++n) acc_o[n] = (f32x4){0.f, 0.f, 0.f, 0.f};
  f32x4 acc_l = (f32x4){0.f, 0.f, 0.f, 0.f};
  float m_r[4] = {-1e30f, -1e30f, -1e30f, -1e30f};

  const short one_bf = (short)0x3F80;
  const bf16x8 ones = {one_bf, one_bf, one_bf, one_bf,
                       one_bf, one_bf, one_bf, one_bf};

  int cur = 0;
  for (int jt = jstart; jt >= jend; --jt) {
    const int tp = it - jt;
    const int j0 = jt * 64;

    // --- top stages: K(jt)->Kb, V(jt)->Vb (consumed this step after MID bar);
    //     R(jt-1)->Rb[cur^1] (consumed next step)
#pragma unroll
    for (int i = 0; i < 2; ++i) {
      const int LB = (i * 256 + tid) * 16, row = LB >> 7, rb_ = LB & 127;
      const int tb = rb_ ^ ((row & 7) << 4);
      gload16((const char*)kb + ((size_t)(j0 + row) * NH + h * 64) * 2 + tb,
              (char*)Kb + LB);
      gload16((const char*)vt + ((size_t)(h * 64 + row) * S + j0) * 2 + tb,
              (char*)Vb + LB);
      if (jt > jend)
        gload16((const char*)rb +
                    ((size_t)(S - 1 - 64 * (tp + 1) - row) * NH + h * 64) * 2 +
                    tb,
                (char*)Rb[cur ^ 1] + LB);
    }

    // --- BD(tp) from Rb[cur] (resident since last step) -> BDb[tp&1]
    f32x4 bd[4];
#pragma unroll
    for (int n = 0; n < 4; ++n) bd[n] = (f32x4){0.f, 0.f, 0.f, 0.f};
#pragma unroll
    for (int ks = 0; ks < 2; ++ks) {
      bf16x8 rf[4];
#pragma unroll
      for (int n = 0; n < 4; ++n)
        rf[n] = ldsT(Rb[cur], n * 16 + (l & 15), ks * 64 + (l >> 4) * 16);
      __builtin_amdgcn_s_setprio(1);
#pragma unroll
      for (int n = 0; n < 4; ++n)
        bd[n] = __builtin_amdgcn_mfma_f32_16x16x32_bf16(qrf[ks], rf[n], bd[n],
                                                        0, 0, 0);
      __builtin_amdgcn_s_setprio(0);
    }
    {
      char* B = (char*)BDb + (tp & 1) * 8704;
#pragma unroll
      for (int n = 0; n < 4; ++n)
#pragma unroll
        for (int r = 0; r < 4; ++r)
          *(ushort*)(B + (fr_base + r) * 136 + (n * 16 + (l & 15)) * 2) =
              f2bf(bd[n][r]);
    }

    __syncthreads();  // MID: drains K/V/R gloads; K,V now visible

    // --- AC from Kb
    f32x4 sa[4];
#pragma unroll
    for (int n = 0; n < 4; ++n) sa[n] = (f32x4){0.f, 0.f, 0.f, 0.f};
#pragma unroll
    for (int ks = 0; ks < 2; ++ks) {
      bf16x8 kf[4];
#pragma unroll
      for (int n = 0; n < 4; ++n)
        kf[n] = ldsT(Kb, n * 16 + (l & 15), ks * 64 + (l >> 4) * 16);
      __builtin_amdgcn_s_setprio(1);
#pragma unroll
      for (int n = 0; n < 4; ++n)
        sa[n] = __builtin_amdgcn_mfma_f32_16x16x32_bf16(qwf[ks], kf[n], sa[n],
                                                        0, 0, 0);
      __builtin_amdgcn_s_setprio(0);
    }

    // --- shear BD + mask + online softmax (log2 space, defer-max THR=8)
    const char* Bnew = (const char*)BDb + (tp & 1) * 8704;
    const char* Bold = (const char*)BDb + ((tp & 1) ^ 1) * 8704;
    float p[4][4];
    float rmax[4] = {-1e30f, -1e30f, -1e30f, -1e30f};
#pragma unroll
    for (int n = 0; n < 4; ++n)
#pragma unroll
      for (int r = 0; r < 4; ++r) {
        const int fr = fr_base + r;
        const int jj = n * 16 + (l & 15);
        const int u = 64 + fr - jj;
        const float bdv = bf2f(*(const ushort*)(
            (u >= 64) ? Bnew + fr * 136 + (u - 64) * 2
                      : Bold + fr * 136 + u * 2));
        float s = sa[n][r] + bdv;  // log2 units (q pre-scaled by QSCALE)
        if (tp == 0 && jj > fr) s = -1e30f;
        p[n][r] = s;
        rmax[r] = fmaxf(rmax[r], s);
      }
#pragma unroll
    for (int off = 1; off < 16; off <<= 1)
#pragma unroll
      for (int r = 0; r < 4; ++r)
        rmax[r] = fmaxf(rmax[r], __shfl_xor(rmax[r], off, 64));
    int grow = 0;
#pragma unroll
    for (int r = 0; r < 4; ++r) grow |= (rmax[r] > m_r[r] + 8.f);
    if (__any(grow)) {
      float corr[4];
#pragma unroll
      for (int r = 0; r < 4; ++r) {
        const float mn = fmaxf(m_r[r], rmax[r]);
        corr[r] = __builtin_exp2f(m_r[r] - mn);
        m_r[r] = mn;
      }
#pragma unroll
      for (int r = 0; r < 4; ++r) acc_l[r] *= corr[r];
#pragma unroll
      for (int n = 0; n < 4; ++n)
#pragma unroll
        for (int r = 0; r < 4; ++r) acc_o[n][r] *= corr[r];
    }
#pragma unroll
    for (int n = 0; n < 4; ++n)
#pragma unroll
      for (int r = 0; r < 4; ++r) p[n][r] = __builtin_exp2f(p[n][r] - m_r[r]);

    // --- P -> dead BD slot (Bold consumed above; wave-private rows; per-wave
    //     DS ordering + data dependence (p depends on all shear reads) => safe
    {
      char* P = (char*)BDb + ((tp & 1) ^ 1) * 8704;
#pragma unroll
      for (int n = 0; n < 4; ++n)
#pragma unroll
        for (int r = 0; r < 4; ++r) {
          const int row16 = (l >> 4) * 4 + r;
          const int colb = (n * 16 + (l & 15)) * 2;
          *(ushort*)(P + (w * 16 + row16) * 136 +
                     (colb ^ ((row16 & 7) << 4))) = f2bf(p[n][r]);
        }
    }

    // --- PV + l accumulation
#pragma unroll
    for (int ks = 0; ks < 2; ++ks) {
      const int prow = l & 15;
      const bf16x8 pf = *(const bf16x8*)(
          (const char*)BDb + ((tp & 1) ^ 1) * 8704 + (w * 16 + prow) * 136 +
          ((ks * 64 + (l >> 4) * 16) ^ ((prow & 7) << 4)));
      bf16x8 vf[4];
#pragma unroll
      for (int n = 0; n < 4; ++n)
        vf[n] = ldsT(Vb, n * 16 + (l & 15), ks * 64 + (l >> 4) * 16);
      __builtin_amdgcn_s_setprio(1);
#pragma unroll
      for (int n = 0; n < 4; ++n)
        acc_o[n] = __builtin_amdgcn_mfma_f32_16x16x32_bf16(pf, vf[n], acc_o[n],
                                                           0, 0, 0);
      acc_l = __builtin_amdgcn_mfma_f32_16x16x32_bf16(pf, ones, acc_l, 0, 0, 0);
      __builtin_amdgcn_s_setprio(0);
    }
    __syncthreads();  // END: protect Kb/Vb (and Rb[cur]) before next stages
    cur ^= 1;
  }

  // --- partial epilogue (unnormalized)
#pragma unroll
  for (int n = 0; n < 4; ++n)
#pragma unroll
    for (int r = 0; r < 4; ++r)
      accX[(size_t)(i0 + fr_base + r) * NH + h * 64 + n * 16 + (l & 15)] =
          acc_o[n][r];
  if ((l & 15) == 0)
#pragma unroll
    for (int r = 0; r < 4; ++r) {
      mX[(i0 + fr_base + r) * H + h] = m_r[r];
      lX[(i0 + fr_base + r) * H + h] = acc_l[r];
    }
}

// ---------------------------------------------------------------------------
// combine halves (m values in log2 space)
// ---------------------------------------------------------------------------
__global__ __launch_bounds__(256) void combine_halves(
    const float* __restrict__ accA, const float* __restrict__ accB,
    const float* __restrict__ mA, const float* __restrict__ lA,
    const float* __restrict__ mB, const float* __restrict__ lB,
    ushort* __restrict__ ab) {
  const int idx = blockIdx.x * 256 + threadIdx.x;
  const int base = idx * 4;
  const int i = base >> 10;
  const int h = (base & 1023) >> 6;
  const float4 a = *(const float4*)(accA + base);
  const float4 b = *(const float4*)(accB + base);
  const float ma = mA[i * H + h], la = lA[i * H + h];
  const float mb = mB[i * H + h], lb = lB[i * H + h];
  const float M = fmaxf(ma, mb);
  const float ea = __builtin_exp2f(ma - M), eb = __builtin_exp2f(mb - M);
  const float inv = 1.f / (la * ea + lb * eb);
  ushort4 u;
  u.x = f2bf((a.x * ea + b.x * eb) * inv);
  u.y = f2bf((a.y * ea + b.y * eb) * inv);
  u.z = f2bf((a.z * ea + b.z * eb) * inv);
  u.w = f2bf((a.w * ea + b.w * eb) * inv);
  *(ushort4*)(ab + base) = u;
}

// ---------------------------------------------------------------------------
extern "C" void kernel_launch(void* const* d_in, const int* in_sizes, int n_in,
                              void* d_out, int out_size, void* d_ws,
                              size_t ws_size, hipStream_t stream) {
  const float* inq = (const float*)d_in[0];
  const float* pos = (const float*)d_in[1];
  const float* rwb = (const float*)d_in[2];
  const float* rrb = (const float*)d_in[3];
  const float* Wq = (const float*)d_in[4];
  const float* bq = (const float*)d_in[5];
  const float* Wk = (const float*)d_in[6];
  const float* bk = (const float*)d_in[7];
  const float* Wv = (const float*)d_in[8];
  const float* bv = (const float*)d_in[9];
  const float* Wr = (const float*)d_in[10];
  const float* br = (const float*)d_in[11];
  const float* Wo = (const float*)d_in[12];
  const float* bo = (const float*)d_in[13];

  char* ws = (char*)d_ws;
  const size_t MB = 1024 * 1024;
  ushort* A_bf = (ushort*)(ws + 0 * MB);   // [S][F] bf16; later reused as ab
  ushort* P_bf = (ushort*)(ws + 4 * MB);   // [S][F] bf16 (dead after QKVR GEMM)
  ushort* Wqkv = (ushort*)(ws + 8 * MB);   // [3072][1024] (dead after GEMM)
  ushort* Wrt = (ushort*)(ws + 14 * MB);   // [NH][F]
  ushort* Wot = (ushort*)(ws + 16 * MB);   // [F][NH]
  ushort* qwp = (ushort*)(ws + 18 * MB);   // [S][NH]
  ushort* qrp = (ushort*)(ws + 22 * MB);
  ushort* kbp = (ushort*)(ws + 26 * MB);
  ushort* vtp = (ushort*)(ws + 30 * MB);   // [NH][S]
  ushort* rbp = (ushort*)(ws + 34 * MB);
  float* mlA = (float*)(ws + 4 * MB);      // aliases P_bf (dead by attn)
  float* mA = mlA + 0 * 32768;
  float* lA = mlA + 1 * 32768;
  float* mB = mlA + 2 * 32768;
  float* lB = mlA + 3 * 32768;
  float* accA = (float*)(ws + 6 * MB);     // aliases Wqkv region (dead by attn)
  float* accB = (float*)(ws + 38 * MB);
  ushort* abp = A_bf;

  prep<<<5376, 256, 0, stream>>>(inq, pos, Wq, Wk, Wv, Wr, Wo, A_bf, P_bf,
                                 Wqkv, Wrt, Wot);

  mm128<0><<<dim3(24, 16, 2), 256, 0, stream>>>(
      A_bf, P_bf, Wqkv, Wrt, bq, rwb, rrb, bk, bv, br, qwp, qrp, kbp, vtp, rbp,
      nullptr);

  attn_mfma<<<1024, 256, 0, stream>>>(qwp, qrp, kbp, vtp, rbp, accA, accB, mA,
                                      lA, mB, lB);
  combine_halves<<<2048, 256, 0, stream>>>(accA, accB, mA, lA, mB, lB, abp);

  mm128<1><<<dim3(8, 16, 1), 256, 0, stream>>>(
      abp, nullptr, Wot, nullptr, bo, nullptr, nullptr, nullptr, nullptr,
      nullptr, nullptr, nullptr, nullptr, nullptr, nullptr, (float*)d_out);
}